// Round 9
// baseline (95.886 us; speedup 1.0000x reference)
//
#include <hip/hip_runtime.h>
#include <hip/hip_bf16.h>

namespace {

constexpr int kB = 8, kT = 64, kE = 4, kD = 256, kH = 1024;
constexpr int kNC = 4;            // H-chunks per (t,e) -> grid 1024
constexpr int kHc = kH / kNC;     // 256

typedef float floatx4 __attribute__((ext_vector_type(4)));

__device__ __forceinline__ float gelu_exact(float v) {
  return 0.5f * v * (1.0f + erff(v * 0.70710678118654752f));
}

__device__ __forceinline__ float4 ntload4(const float4* p) {
  const floatx4 v = __builtin_nontemporal_load(reinterpret_cast<const floatx4*>(p));
  return make_float4(v.x, v.y, v.z, v.w);
}

__global__ __launch_bounds__(256, 4)
void moe_ffn_kernel(const float* __restrict__ x,
                    const float* __restrict__ fc1,
                    const float* __restrict__ b1,
                    const float* __restrict__ fc2,
                    const float* __restrict__ b2,
                    const float* __restrict__ Wr,
                    const float* __restrict__ br,
                    float* __restrict__ out) {
  __shared__ float xs[kB][kD];      // 8 KB
  __shared__ float hid[kB][kHc];    // 8 KB
  __shared__ float red[kB][kD];     // 8 KB
  __shared__ float gates_s[kB];

  const int tid  = threadIdx.x;
  const int bid  = blockIdx.x;      // te * kNC + c
  const int te   = bid >> 2;
  const int c    = bid & 3;
  const int t    = te >> 2;
  const int h0   = c * kHc;
  const int wave = tid >> 6, lane = tid & 63;

  // ---- stage x[b, t, :] into LDS as float4 (cached loads) ----
  {
    const float4* __restrict__ xsrc = reinterpret_cast<const float4*>(x);
    float4* xdst = reinterpret_cast<float4*>(&xs[0][0]);
#pragma unroll
    for (int i = 0; i < 2; ++i) {
      const int f = i * 256 + tid;            // 0..511 float4s
      const int b = f >> 6, d4 = f & 63;
      xdst[f] = xsrc[(size_t)(b * kT + t) * (kD / 4) + d4];
    }
  }
  __syncthreads();

  // ---- router gates: wave w computes b = 2w, 2w+1 ----
  {
    const float* __restrict__ wr = Wr + (size_t)te * kD;
    const float w0 = wr[lane], w1 = wr[lane + 64], w2 = wr[lane + 128], w3 = wr[lane + 192];
#pragma unroll
    for (int bb = 0; bb < 2; ++bb) {
      const int b = wave * 2 + bb;
      float p = xs[b][lane] * w0 + xs[b][lane + 64] * w1 +
                xs[b][lane + 128] * w2 + xs[b][lane + 192] * w3;
#pragma unroll
      for (int off = 32; off; off >>= 1) p += __shfl_xor(p, off);
      if (lane == 0) {
        const float g = p + br[te];
        gates_s[b] = g > 0.0f ? g : 0.0f;
      }
    }
  }

  // ---- phase 1: wave owns d-quarter [64*wave, +64); lane owns h = h0+4*lane..+3 ----
  // fc1 loads: CACHED dwordx4 — fc1 (256 MiB) is the L3-resident partition.
  float4 acc[kB];
#pragma unroll
  for (int b = 0; b < kB; ++b) acc[b] = make_float4(0.f, 0.f, 0.f, 0.f);
  {
    const float4* __restrict__ wp =
        reinterpret_cast<const float4*>(fc1 + (size_t)te * (kD * kH));  // [d][kH/4]
    const int hq = (h0 >> 2) + lane;
    const int d0 = wave * 64;
    for (int dg = 0; dg < 16; ++dg) {
      const int d = d0 + dg * 4;
      const float4 wv0 = wp[(size_t)(d + 0) * (kH / 4) + hq];
      const float4 wv1 = wp[(size_t)(d + 1) * (kH / 4) + hq];
      const float4 wv2 = wp[(size_t)(d + 2) * (kH / 4) + hq];
      const float4 wv3 = wp[(size_t)(d + 3) * (kH / 4) + hq];
#pragma unroll
      for (int b = 0; b < kB; ++b) {
        const float4 xv = *reinterpret_cast<const float4*>(&xs[b][d]);
        acc[b].x = fmaf(xv.x, wv0.x, acc[b].x);
        acc[b].y = fmaf(xv.x, wv0.y, acc[b].y);
        acc[b].z = fmaf(xv.x, wv0.z, acc[b].z);
        acc[b].w = fmaf(xv.x, wv0.w, acc[b].w);
        acc[b].x = fmaf(xv.y, wv1.x, acc[b].x);
        acc[b].y = fmaf(xv.y, wv1.y, acc[b].y);
        acc[b].z = fmaf(xv.y, wv1.z, acc[b].z);
        acc[b].w = fmaf(xv.y, wv1.w, acc[b].w);
        acc[b].x = fmaf(xv.z, wv2.x, acc[b].x);
        acc[b].y = fmaf(xv.z, wv2.y, acc[b].y);
        acc[b].z = fmaf(xv.z, wv2.z, acc[b].z);
        acc[b].w = fmaf(xv.z, wv2.w, acc[b].w);
        acc[b].x = fmaf(xv.w, wv3.x, acc[b].x);
        acc[b].y = fmaf(xv.w, wv3.y, acc[b].y);
        acc[b].z = fmaf(xv.w, wv3.z, acc[b].z);
        acc[b].w = fmaf(xv.w, wv3.w, acc[b].w);
      }
    }
  }
  // cross-wave combine into hid by rotation (sequential b128, conflict-free)
#pragma unroll
  for (int g = 0; g < 4; ++g) {
    if (wave == g) {
#pragma unroll
      for (int b = 0; b < kB; ++b) {
        float4* hp = reinterpret_cast<float4*>(&hid[b][0]) + lane;
        if (g == 0) {
          *hp = acc[b];
        } else {
          float4 v = *hp;
          v.x += acc[b].x; v.y += acc[b].y; v.z += acc[b].z; v.w += acc[b].w;
          *hp = v;
        }
      }
    }
    __syncthreads();
  }
  // bias + gelu pass: thread owns column tid
  {
    const float bias = b1[(size_t)te * kH + h0 + tid];
#pragma unroll
    for (int b = 0; b < kB; ++b) hid[b][tid] = gelu_exact(hid[b][tid] + bias);
  }
  __syncthreads();

  // ---- phase 2: lane owns d = 4*lane..+3; wave owns h-strip [h0+64*wave, +64) ----
  // fc2 loads: NON-TEMPORAL dwordx4 — streams from HBM without evicting fc1.
  float4 acc2[kB];
#pragma unroll
  for (int b = 0; b < kB; ++b) acc2[b] = make_float4(0.f, 0.f, 0.f, 0.f);
  {
    const float4* __restrict__ wp =
        reinterpret_cast<const float4*>(fc2 + (size_t)te * (kH * kD));  // [h][kD/4]
    const int hb = wave * 64;
    for (int hg = 0; hg < 16; ++hg) {
      const int hl = hb + hg * 4;
      const int h  = h0 + hl;
      const float4 wv0 = ntload4(wp + (size_t)(h + 0) * (kD / 4) + lane);
      const float4 wv1 = ntload4(wp + (size_t)(h + 1) * (kD / 4) + lane);
      const float4 wv2 = ntload4(wp + (size_t)(h + 2) * (kD / 4) + lane);
      const float4 wv3 = ntload4(wp + (size_t)(h + 3) * (kD / 4) + lane);
#pragma unroll
      for (int b = 0; b < kB; ++b) {
        const float4 hv = *reinterpret_cast<const float4*>(&hid[b][hl]);
        acc2[b].x = fmaf(hv.x, wv0.x, acc2[b].x);
        acc2[b].y = fmaf(hv.x, wv0.y, acc2[b].y);
        acc2[b].z = fmaf(hv.x, wv0.z, acc2[b].z);
        acc2[b].w = fmaf(hv.x, wv0.w, acc2[b].w);
        acc2[b].x = fmaf(hv.y, wv1.x, acc2[b].x);
        acc2[b].y = fmaf(hv.y, wv1.y, acc2[b].y);
        acc2[b].z = fmaf(hv.y, wv1.z, acc2[b].z);
        acc2[b].w = fmaf(hv.y, wv1.w, acc2[b].w);
        acc2[b].x = fmaf(hv.z, wv2.x, acc2[b].x);
        acc2[b].y = fmaf(hv.z, wv2.y, acc2[b].y);
        acc2[b].z = fmaf(hv.z, wv2.z, acc2[b].z);
        acc2[b].w = fmaf(hv.z, wv2.w, acc2[b].w);
        acc2[b].x = fmaf(hv.w, wv3.x, acc2[b].x);
        acc2[b].y = fmaf(hv.w, wv3.y, acc2[b].y);
        acc2[b].z = fmaf(hv.w, wv3.z, acc2[b].z);
        acc2[b].w = fmaf(hv.w, wv3.w, acc2[b].w);
      }
    }
  }
  // cross-wave combine into red by rotation
#pragma unroll
  for (int g = 0; g < 4; ++g) {
    if (wave == g) {
#pragma unroll
      for (int b = 0; b < kB; ++b) {
        float4* rp = reinterpret_cast<float4*>(&red[b][0]) + lane;
        if (g == 0) {
          *rp = acc2[b];
        } else {
          float4 v = *rp;
          v.x += acc2[b].x; v.y += acc2[b].y; v.z += acc2[b].z; v.w += acc2[b].w;
          *rp = v;
        }
      }
    }
    __syncthreads();
  }

  // ---- epilogue: thread owns d = tid; gate-scale and accumulate over e ----
  {
    const float b2v = (c == 0) ? b2[(size_t)te * kD + tid] : 0.f;
#pragma unroll
    for (int b = 0; b < kB; ++b)
      atomicAdd(&out[((size_t)b * kT + t) * kD + tid], gates_s[b] * (red[b][tid] + b2v));

    if (c == 0 && tid == 0) {
      float gs = 0.f;
#pragma unroll
      for (int b = 0; b < kB; ++b) gs += gates_s[b];
      atomicAdd(&out[(size_t)kB * kT * kD], 0.01f * gs * (1.0f / (kB * kT)));
    }
  }
}

}  // namespace

extern "C" void kernel_launch(void* const* d_in, const int* in_sizes, int n_in,
                              void* d_out, int out_size, void* d_ws, size_t ws_size,
                              hipStream_t stream) {
  const float* x   = (const float*)d_in[0];
  const float* fc1 = (const float*)d_in[1];
  const float* b1  = (const float*)d_in[2];
  const float* fc2 = (const float*)d_in[3];
  const float* b2  = (const float*)d_in[4];
  const float* Wr  = (const float*)d_in[5];
  const float* br  = (const float*)d_in[6];
  float* out = (float*)d_out;

  // Zero the accumulation target every call (graph replays must be
  // deterministic; harness does not re-poison between replays).
  (void)hipMemsetAsync(d_out, 0, (size_t)out_size * sizeof(float), stream);

  moe_ffn_kernel<<<dim3(kT * kE * kNC), dim3(256), 0, stream>>>(
      x, fc1, b1, fc2, b2, Wr, br, out);
}